// Round 11
// baseline (246.917 us; speedup 1.0000x reference)
//
#include <hip/hip_runtime.h>
#include <hip/hip_bf16.h>

typedef __bf16 bf16_t;
typedef __attribute__((ext_vector_type(8))) __bf16 bf16x8;
typedef __attribute__((ext_vector_type(4))) __bf16 bf16x4;
typedef __attribute__((ext_vector_type(4))) float f32x4;

static __device__ __forceinline__ f32x4 mfma16(bf16x8 a, bf16x8 b, f32x4 c) {
  return __builtin_amdgcn_mfma_f32_16x16x32_bf16(a, b, c, 0, 0, 0);
}

// async global->LDS, 16 B per lane. LDS dest is wave-uniform base + lane*16.
static __device__ __forceinline__ void async16(const void* g, void* l) {
  __builtin_amdgcn_global_load_lds(
      (const __attribute__((address_space(1))) void*)g,
      (__attribute__((address_space(3))) void*)l, 16, 0, 0);
}

static __device__ __forceinline__ bf16x8 load8f(const float* __restrict__ fp) {
  float4 a = *(const float4*)fp;
  float4 b = *(const float4*)(fp + 4);
  bf16x8 r;
  r[0] = (bf16_t)a.x; r[1] = (bf16_t)a.y; r[2] = (bf16_t)a.z; r[3] = (bf16_t)a.w;
  r[4] = (bf16_t)b.x; r[5] = (bf16_t)b.y; r[6] = (bf16_t)b.z; r[7] = (bf16_t)b.w;
  return r;
}

// ---------------------------------------------------------------------------
// merged prep kernel (r10, kept: ~20us win from saved launch boundaries).
// invperm + convert_x + convert_w in one launch; flat grid, branch by range.
// ---------------------------------------------------------------------------
__global__ __launch_bounds__(256) void prep_kernel(
    const float* __restrict__ x, bf16_t* __restrict__ Xp,
    const int* __restrict__ perm, int* __restrict__ invp,
    const float* Wq, const float* bq, const float* Wk, const float* bk,
    const float* Wv, const float* bv, const float* Wo, const float* bo,
    bf16_t* __restrict__ Wb, bf16_t* __restrict__ bb,
    int S, int H, int M)
{
  const int nxc = (M * H) / 2048;              // convert_x blocks (8192)
  const int nw  = (H * H) / 2048 + 1;          // per-matrix W blocks (129)
  const int bx = blockIdx.x;
  if (bx < nxc) {
    // x -> bf16, pre-applying the permutation: Xp[b*S+i] = x[b*S+perm[i]]
    int m = bx * 4 + (threadIdx.x >> 6);
    int c = (threadIdx.x & 63) * 8;
    int b = m / S, i = m - b * S;
    long src = ((long)b * S + perm[i]) * H + c;
    *(bf16x8*)&Xp[(long)m * H + c] = load8f(x + src);
  } else if (bx < nxc + 4 * nw) {
    int t = bx - nxc;
    int z = t / nw, wx = t - z * nw;
    const float* W  = (z == 0) ? Wq : (z == 1) ? Wk : (z == 2) ? Wv : Wo;
    const float* bi = (z == 0) ? bq : (z == 1) ? bk : (z == 2) ? bv : bo;
    bf16_t* dst = Wb + (long)z * H * H;
    if (wx < nw - 1) {
      long e = (long)wx * 2048 + threadIdx.x * 8;
      *(bf16x8*)&dst[e] = load8f(W + e);
    } else {
      int e = threadIdx.x * 8;
      if (e < H) *(bf16x8*)&bb[z * H + e] = load8f(bi + e);
    }
  } else {
    int i = (bx - nxc - 4 * nw) * 256 + threadIdx.x;
    if (i < S) invp[perm[i]] = i;
  }
}

// ---------------------------------------------------------------------------
// GEMM core: r7 VERBATIM (r3 4-phase counted-vmcnt pipeline + r5 coalesced
// LDS-transpose epilogues, ALL 8 barriers/tile). r10's mid-tile PH_END
// removal REVERTED: it was correctness-safe but cost 17us on qkv — the
// lockstep barriers keep the 8 waves phase-aligned so the single LDS pipe
// serves homogeneous ds_read bursts; skewed waves made every PH_MID a
// global re-convergence on the slowest wave. Barriers here are load-bearing
// for THROUGHPUT, not just safety.
// BM=BN=256, BK=64, 512 threads = 8 waves (2M x 4N), 1 block/CU (proven:
// r8 spill disaster at 2/CU; r0 128^2 slower).
// MODE 0: bf16 C tile, row-major out (Q/K)
// MODE 1: f32 C tile (final out)
// MODE 2: writes V^T as [b][head][chan][tok]
// GATHER: A row m is gathered from row b*S + invp[m%S]
// ---------------------------------------------------------------------------
template<int MODE, bool GATHER>
__device__ __forceinline__ void gemm_core(
    unsigned char* __restrict__ smem,   // 128 KB
    const bf16_t* __restrict__ A, const bf16_t* __restrict__ W,
    const bf16_t* __restrict__ bias, void* __restrict__ C,
    const int* __restrict__ invp, int N, int K, int S)
{
  bf16_t (*At)[64] = (bf16_t(*)[64])smem;             // [512][64]
  bf16_t (*Bt)[64] = (bf16_t(*)[64])(smem + 65536);   // [512][64]

  const int bm = blockIdx.x * 256, bn = blockIdx.y * 256;
  const int tid = threadIdx.x, lane = tid & 63, w = tid >> 6;   // 8 waves
  const int qd = lane >> 4, ln = lane & 15, l7 = ln & 7;
  const int wm = w & 1, wn = w >> 1;            // 2M x 4N wave grid
  const int srow = lane >> 3;                   // 0..7 (row&7 of staged row)
  const int scol = ((lane & 7) ^ srow) * 8;     // swizzled global fetch chunk

  int ga[2][2], gb[2][2];
#pragma unroll
  for (int u = 0; u < 2; ++u) {
    int ix = w + 8 * u;                         // 0..15
    ga[0][u] = (ix & 7) + ((ix >> 3) << 4);
    ga[1][u] = ga[0][u] + 8;
    gb[0][u] = (ix & 3) + ((ix >> 2) << 3);
    gb[1][u] = gb[0][u] + 4;
  }
  long aoff[2][2], woff[2][2];
#pragma unroll
  for (int h = 0; h < 2; ++h)
#pragma unroll
    for (int u = 0; u < 2; ++u) {
      int mg = bm + ga[h][u] * 8 + srow;
      if (GATHER) { int b_ = mg / S; aoff[h][u] = ((long)b_ * S + invp[mg - b_ * S]) * K + scol; }
      else        { aoff[h][u] = (long)mg * K + scol; }
      woff[h][u] = (long)(bn + gb[h][u] * 8 + srow) * K + scol;
    }

  f32x4 acc[2][2][4][2];
#pragma unroll
  for (int a = 0; a < 2; ++a)
#pragma unroll
    for (int b = 0; b < 2; ++b)
#pragma unroll
      for (int i = 0; i < 4; ++i)
#pragma unroll
        for (int j = 0; j < 2; ++j)
          acc[a][b][i][j] = (f32x4){0.f, 0.f, 0.f, 0.f};

  bf16x8 af[4][2], bfr[2][2];
  const int NT = K >> 6;                         // 8 K-tiles for K=512

#define LOAD_A(RH)                                                            \
  _Pragma("unroll") for (int i = 0; i < 4; ++i)                               \
  _Pragma("unroll") for (int ks = 0; ks < 2; ++ks)                            \
    af[i][ks] = *(const bf16x8*)&At[sb + wm * 128 + (RH) * 64 + 16 * i + ln]  \
                                   [((ks * 4 + qd) ^ l7) * 8];
#define LOAD_B(CH)                                                            \
  _Pragma("unroll") for (int j = 0; j < 2; ++j)                               \
  _Pragma("unroll") for (int ks = 0; ks < 2; ++ks)                            \
    bfr[j][ks] = *(const bf16x8*)&Bt[sb + wn * 64 + (CH) * 32 + 16 * j + ln]  \
                                    [((ks * 4 + qd) ^ l7) * 8];
#define STAGE_A(HH)                                                           \
  if (st) {                                                                   \
    async16(&A[aoff[HH][0] + k2], &At[so + ga[HH][0] * 8][0]);                \
    async16(&A[aoff[HH][1] + k2], &At[so + ga[HH][1] * 8][0]);                \
  }
#define STAGE_B(CH)                                                           \
  if (st) {                                                                   \
    async16(&W[woff[CH][0] + k2], &Bt[so + gb[CH][0] * 8][0]);                \
    async16(&W[woff[CH][1] + k2], &Bt[so + gb[CH][1] * 8][0]);                \
  }
#define MFMA_Q(RH, CH)                                                        \
  __builtin_amdgcn_s_setprio(1);                                              \
  _Pragma("unroll") for (int i = 0; i < 4; ++i)                               \
  _Pragma("unroll") for (int j = 0; j < 2; ++j)                               \
  _Pragma("unroll") for (int ks = 0; ks < 2; ++ks) {                          \
    if (MODE == 2) acc[RH][CH][i][j] = mfma16(af[i][ks], bfr[j][ks], acc[RH][CH][i][j]); \
    else           acc[RH][CH][i][j] = mfma16(bfr[j][ks], af[i][ks], acc[RH][CH][i][j]); \
  }                                                                           \
  __builtin_amdgcn_s_setprio(0);
#define GATE2 asm volatile("s_waitcnt vmcnt(2)" ::: "memory")
#define GATE0 asm volatile("s_waitcnt vmcnt(0)" ::: "memory")
#define PH_MID                                                                \
  __builtin_amdgcn_s_barrier();                                               \
  asm volatile("s_waitcnt lgkmcnt(0)" ::: "memory");
#define PH_END __builtin_amdgcn_s_barrier();

  // prologue: stage tile 0 into slot 0 in deadline order A0,B0,B1,A1
  async16(&A[aoff[0][0]], &At[ga[0][0] * 8][0]);
  async16(&A[aoff[0][1]], &At[ga[0][1] * 8][0]);
  async16(&W[woff[0][0]], &Bt[gb[0][0] * 8][0]);
  async16(&W[woff[0][1]], &Bt[gb[0][1] * 8][0]);
  async16(&W[woff[1][0]], &Bt[gb[1][0] * 8][0]);
  async16(&W[woff[1][1]], &Bt[gb[1][1] * 8][0]);
  async16(&A[aoff[1][0]], &At[ga[1][0] * 8][0]);
  async16(&A[aoff[1][1]], &At[ga[1][1] * 8][0]);
  GATE2;
  __builtin_amdgcn_s_barrier();

  for (int kt = 0; kt < NT; ++kt) {
    const int sb = (kt & 1) << 8;          // compute-slot row base
    const int so = ((kt + 1) & 1) << 8;    // stage-slot row base
    const long k2 = (long)(kt + 1) << 6;
    const bool st = (kt + 1 < NT);

    // ---- phase 1: (rh=0, ch=0) ----
    GATE2;
    LOAD_A(0)
    LOAD_B(0)
    STAGE_A(0)
    PH_MID
    MFMA_Q(0, 0)
    PH_END
    // ---- phase 2: (rh=0, ch=1) ----
    if (st) { GATE2; } else { GATE0; }     // last tile: drain once here
    LOAD_B(1)
    STAGE_B(0)
    PH_MID
    MFMA_Q(0, 1)
    PH_END
    // ---- phase 3: (rh=1, ch=1) ----
    if (st) { GATE2; }
    LOAD_A(1)
    STAGE_B(1)
    PH_MID
    MFMA_Q(1, 1)
    PH_END
    // ---- phase 4: (rh=1, ch=0) ----
    if (st) { GATE2; }
    LOAD_B(0)
    STAGE_A(1)
    PH_MID
    MFMA_Q(1, 0)
    PH_END
  }

#undef LOAD_A
#undef LOAD_B
#undef STAGE_A
#undef STAGE_B
#undef MFMA_Q
#undef GATE2
#undef GATE0
#undef PH_MID
#undef PH_END

  // ---- coalesced epilogues via 16B-swizzled LDS transpose scratch ----
  if (MODE == 0) {
#pragma unroll
    for (int rh = 0; rh < 2; ++rh)
#pragma unroll
      for (int ch = 0; ch < 2; ++ch)
#pragma unroll
        for (int j = 0; j < 2; ++j) {
          bf16x4 b4 = *(const bf16x4*)&bias[bn + wn * 64 + ch * 32 + 16 * j + 4 * qd];
          int c16 = wn * 8 + ch * 4 + 2 * j + (qd >> 1);
#pragma unroll
          for (int i = 0; i < 4; ++i) {
            int m = wm * 128 + rh * 64 + 16 * i + ln;
            bf16x4 pk;
#pragma unroll
            for (int r = 0; r < 4; ++r) pk[r] = (bf16_t)(acc[rh][ch][i][j][r] + (float)b4[r]);
            *(bf16x4*)(smem + m * 512 + ((c16 ^ l7) * 16) + (qd & 1) * 8) = pk;
          }
        }
    __syncthreads();
#pragma unroll
    for (int k = 0; k < 16; ++k) {
      int row = w * 32 + 2 * k + (lane >> 5);
      int c = lane & 31;
      bf16x8 v = *(const bf16x8*)(smem + row * 512 + ((c ^ (row & 7)) * 16));
      *(bf16x8*)&((bf16_t*)C)[(long)(bm + row) * N + bn + c * 8] = v;
    }
  } else if (MODE == 1) {
#pragma unroll
    for (int rh = 0; rh < 2; ++rh) {
      if (rh) __syncthreads();
#pragma unroll
      for (int ch = 0; ch < 2; ++ch)
#pragma unroll
        for (int j = 0; j < 2; ++j) {
          bf16x4 b4 = *(const bf16x4*)&bias[bn + wn * 64 + ch * 32 + 16 * j + 4 * qd];
          int c16 = wn * 16 + ch * 8 + 4 * j + qd;
#pragma unroll
          for (int i = 0; i < 4; ++i) {
            int hrow = wm * 64 + 16 * i + ln;
            float4 pk = {acc[rh][ch][i][j][0] + (float)b4[0], acc[rh][ch][i][j][1] + (float)b4[1],
                         acc[rh][ch][i][j][2] + (float)b4[2], acc[rh][ch][i][j][3] + (float)b4[3]};
            *(float4*)(smem + hrow * 1024 + ((c16 ^ l7) * 16)) = pk;
          }
        }
      __syncthreads();
#pragma unroll
      for (int k = 0; k < 16; ++k) {
        int hrow = w + 8 * k;
        float4 v = *(const float4*)(smem + hrow * 1024 + (((lane) ^ (hrow & 7)) * 16));
        int gm = bm + (hrow >> 6) * 128 + rh * 64 + (hrow & 63);
        *(float4*)&((float*)C)[(long)gm * N + bn + lane * 4] = v;
      }
    }
  } else {
    const int heads = S >> 6;
    const int b_ = bm / S;
    const int h0 = (bm - b_ * S) >> 6;          // head base of this block
#pragma unroll
    for (int rh = 0; rh < 2; ++rh)
#pragma unroll
      for (int ch = 0; ch < 2; ++ch)
#pragma unroll
        for (int j = 0; j < 2; ++j) {
          int n = wn * 64 + ch * 32 + 16 * j + ln;
          float bv = (float)bias[bn + n];
#pragma unroll
          for (int i = 0; i < 4; ++i) {
            int c16 = wm * 16 + rh * 8 + 2 * i + (qd >> 1);
            bf16x4 pk;
#pragma unroll
            for (int r = 0; r < 4; ++r) pk[r] = (bf16_t)(acc[rh][ch][i][j][r] + bv);
            *(bf16x4*)(smem + n * 512 + ((c16 ^ l7) * 16) + (qd & 1) * 8) = pk;
          }
        }
    __syncthreads();
#pragma unroll
    for (int k = 0; k < 16; ++k) {
      int h4 = k >> 2;                            // local head (m block)
      int n = (w + 8 * (k & 3)) * 8 + (lane >> 3);
      int tc = lane & 7;                          // 16B tok-chunk
      bf16x8 v = *(const bf16x8*)(smem + n * 512 + (((h4 * 8 + tc) ^ (n & 7)) * 16));
      *(bf16x8*)&((bf16_t*)C)[(((long)(b_ * heads + h0 + h4) * N + bn + n) << 6) + tc * 8] = v;
    }
  }
}

__global__ __launch_bounds__(512, 2) void gemm_qkv_kernel(
    const bf16_t* __restrict__ Xp, const bf16_t* __restrict__ Wb,
    const bf16_t* __restrict__ bb,
    bf16_t* __restrict__ Qp, bf16_t* __restrict__ Kp, bf16_t* __restrict__ Vt,
    int S, int H)
{
  __shared__ __align__(16) unsigned char smem[131072];
  const int z = blockIdx.z;
  if (z < 2)
    gemm_core<0, false>(smem, Xp, Wb + (long)z * H * H, bb + z * H,
                        z ? (void*)Kp : (void*)Qp, nullptr, H, H, S);
  else
    gemm_core<2, false>(smem, Xp, Wb + 2L * H * H, bb + 2 * H, Vt, nullptr, H, H, S);
}

__global__ __launch_bounds__(512, 2) void gemm_o_kernel(
    const bf16_t* __restrict__ Att, const bf16_t* __restrict__ Wb,
    const bf16_t* __restrict__ bb, float* __restrict__ C,
    const int* __restrict__ invp, int S, int H)
{
  __shared__ __align__(16) unsigned char smem[131072];
  gemm_core<1, true>(smem, Att, Wb + 3L * H * H, bb + 3 * H, C, invp, H, H, S);
}

// ---------------------------------------------------------------------------
// attn v2 (r6, kept): 2 blocks/CU. LDS 73 KB via chan-chunked K and V.
// Raw s_barrier + explicit lgkmcnt(0)/vmcnt gates; exposed vmcnt(0) gates
// hide under the co-resident block.
// ---------------------------------------------------------------------------
__global__ __launch_bounds__(256) void attn_kernel(
    const bf16_t* __restrict__ Qp, const bf16_t* __restrict__ Kp,
    const bf16_t* __restrict__ Vt, bf16_t* __restrict__ Att,
    int S, int H)
{
  const int heads = S >> 6;
  const int b = blockIdx.x / heads;
  const int h = blockIdx.x % heads;
  const long qkbase = ((long)b * S + h * 64) * H;
  const long vbase  = (long)(b * heads + h) * H * 64;

  const int tid = threadIdx.x, lane = tid & 63, w = tid >> 6;
  const int qd = lane >> 4, ln = lane & 15;
  const int l7 = ln & 7;

  __shared__ bf16_t Ks[64 * 256];   // 32 KB K chan-chunk; later out-scratch
  __shared__ bf16_t Vs[256 * 64];   // 32 KB V^T chan-chunk
  __shared__ bf16_t P[64][72];      // 9 KB softmax weights

  // stage K chunk0 (chans 0-255)
  for (int u = 0; u < 8; ++u) {
    int row = 16 * w + 2 * u + (lane >> 5);
    int c = lane & 31;
    async16(&Kp[qkbase + (long)row * H + ((c ^ (row & 7)) * 8)],
            &Ks[(16 * w + 2 * u) * 256]);
  }
  asm volatile("" ::: "memory");     // pin K0 first in the vmcnt ledger
  bf16x8 qf[16];
  for (int t = 0; t < 16; ++t)
    qf[t] = *(const bf16x8*)&Qp[qkbase + (long)(16 * w + ln) * H + t * 32 + qd * 8];
  // stage V chunk0 (V^T rows 0-255)
  for (int u = 0; u < 8; ++u) {
    int rowb = 64 * w + 8 * u;
    async16(&Vt[vbase + (long)(rowb + (lane >> 3)) * 64 +
                (((lane & 7) ^ ((lane >> 3) & 7)) * 8)],
            &Vs[rowb * 64]);
  }
  asm volatile("s_waitcnt vmcnt(24)" ::: "memory");   // K0 landed (Q+V0 fly)
  __builtin_amdgcn_s_barrier();

  // QK chunk0: chans 0-255 (t = 0..7)
  f32x4 accs[4];
  for (int j = 0; j < 4; ++j) accs[j] = (f32x4){0.f, 0.f, 0.f, 0.f};
  for (int t = 0; t < 8; ++t)
    for (int j = 0; j < 4; ++j) {
      bf16x8 kf = *(const bf16x8*)&Ks[(16 * j + ln) * 256 + (((t * 4 + qd) ^ l7) * 8)];
      accs[j] = mfma16(qf[t], kf, accs[j]);
    }
  asm volatile("s_waitcnt lgkmcnt(0)" ::: "memory");
  __builtin_amdgcn_s_barrier();       // all waves done reading K0
  // stage K chunk1 (chans 256-511) into the same slab
  for (int u = 0; u < 8; ++u) {
    int row = 16 * w + 2 * u + (lane >> 5);
    int c = lane & 31;
    async16(&Kp[qkbase + (long)row * H + 256 + ((c ^ (row & 7)) * 8)],
            &Ks[(16 * w + 2 * u) * 256]);
  }
  asm volatile("s_waitcnt vmcnt(0)" ::: "memory");    // K1 (and V0) landed
  __builtin_amdgcn_s_barrier();
  // QK chunk1: chans 256-511 (t = 8..15)
  for (int t = 8; t < 16; ++t)
    for (int j = 0; j < 4; ++j) {
      bf16x8 kf = *(const bf16x8*)&Ks[(16 * j + ln) * 256 + ((((t - 8) * 4 + qd) ^ l7) * 8)];
      accs[j] = mfma16(qf[t], kf, accs[j]);
    }

  // register softmax, normalized weights into P (LDS)
  const float rscale = rsqrtf((float)H);
  for (int r = 0; r < 4; ++r) {
    float s[4];
    for (int j = 0; j < 4; ++j) s[j] = accs[j][r] * rscale;
    float mx = fmaxf(fmaxf(s[0], s[1]), fmaxf(s[2], s[3]));
    mx = fmaxf(mx, __shfl_xor(mx, 1));
    mx = fmaxf(mx, __shfl_xor(mx, 2));
    mx = fmaxf(mx, __shfl_xor(mx, 4));
    mx = fmaxf(mx, __shfl_xor(mx, 8));
    float e[4], sum = 0.f;
    for (int j = 0; j < 4; ++j) {
      e[j] = (float)(bf16_t)__expf(s[j] - mx);
      sum += e[j];
    }
    sum += __shfl_xor(sum, 1);
    sum += __shfl_xor(sum, 2);
    sum += __shfl_xor(sum, 4);
    sum += __shfl_xor(sum, 8);
    float rs = 1.f / sum;
    for (int j = 0; j < 4; ++j)
      P[16 * w + qd * 4 + r][16 * j + ln] = (bf16_t)(e[j] * rs);
  }
  asm volatile("s_waitcnt lgkmcnt(0)" ::: "memory");
  __builtin_amdgcn_s_barrier();   // P visible; Ks dead -> scratch; Vs = V0

  unsigned char* scratch = (unsigned char*)Ks;   // [64 rows][512 B]
  const int m = 16 * w + ln;
  const long orow = (long)b * S + h * 64;

#pragma unroll
  for (int half = 0; half < 2; ++half) {
    for (int nc = 0; nc < 2; ++nc) {
      f32x4 acco[8];
      for (int j = 0; j < 8; ++j) acco[j] = (f32x4){0.f, 0.f, 0.f, 0.f};
      for (int ks = 0; ks < 2; ++ks) {
        bf16x8 pf = *(const bf16x8*)&P[m][ks * 32 + qd * 8];
        for (int j = 0; j < 8; ++j) {
          int row = nc * 128 + 16 * j + ln;
          bf16x8 vf = *(const bf16x8*)&Vs[row * 64 + (((ks * 4 + qd) ^ l7) * 8)];
          acco[j] = mfma16(vf, pf, acco[j]);
        }
      }
      for (int j = 0; j < 8; ++j) {
        int c16 = nc * 16 + 2 * j + (qd >> 1);
        bf16x4 pk;
        for (int r = 0; r < 4; ++r) pk[r] = (bf16_t)acco[j][r];
        *(bf16x4*)(scratch + m * 512 + ((c16 ^ l7) * 16) + (qd & 1) * 8) = pk;
      }
    }
    asm volatile("s_waitcnt lgkmcnt(0)" ::: "memory");
    __builtin_amdgcn_s_barrier();     // Vs reads + scratch writes done
    if (half == 0) {
      // stage V chunk1 (V^T rows 256-511) while half0 stores run
      for (int u = 0; u < 8; ++u) {
        int rowb = 64 * w + 8 * u;
        async16(&Vt[vbase + (long)(256 + rowb + (lane >> 3)) * 64 +
                    (((lane & 7) ^ ((lane >> 3) & 7)) * 8)],
                &Vs[rowb * 64]);
      }
    }
    // store this half: contiguous 512 B runs per half-wave
    for (int k = 0; k < 8; ++k) {
      int row = 16 * w + 2 * k + (lane >> 5);
      int c = lane & 31;
      bf16x8 v = *(const bf16x8*)(scratch + row * 512 + ((c ^ (row & 7)) * 16));
      *(bf16x8*)&Att[(orow + row) * H + half * 256 + c * 8] = v;
    }
    if (half == 0) {
      asm volatile("s_waitcnt vmcnt(0)" ::: "memory");  // V1 landed
      __builtin_amdgcn_s_barrier();
    }
  }
}

extern "C" void kernel_launch(void* const* d_in, const int* in_sizes, int n_in,
                              void* d_out, int out_size, void* d_ws, size_t ws_size,
                              hipStream_t stream)
{
  const float* x  = (const float*)d_in[0];
  const float* Wq = (const float*)d_in[1]; const float* bq = (const float*)d_in[2];
  const float* Wk = (const float*)d_in[3]; const float* bk = (const float*)d_in[4];
  const float* Wv = (const float*)d_in[5]; const float* bv = (const float*)d_in[6];
  const float* Wo = (const float*)d_in[7]; const float* bo = (const float*)d_in[8];
  const int* perm = (const int*)d_in[9];

  const int S = in_sizes[9];                 // 4096
  const int H = in_sizes[2];                 // 512
  const int B = in_sizes[0] / (S * H);       // 8
  const int M = B * S;                       // 32768

  size_t bufB = (size_t)M * H * sizeof(bf16_t);          // 32 MB
  size_t wB   = 4 * (size_t)H * H * sizeof(bf16_t);
  size_t need = 256 + 4 * bufB + wB + 4 * H * 2 + (size_t)S * 4;
  if (ws_size < need) return;

  char* p = (char*)d_ws;  p += 256;
  bf16_t* Xp = (bf16_t*)p;  p += bufB;        // aliased as Att after QKV GEMM
  bf16_t* Qp = (bf16_t*)p;  p += bufB;
  bf16_t* Kp = (bf16_t*)p;  p += bufB;
  bf16_t* Vt = (bf16_t*)p;  p += bufB;        // V^T: [b][head][chan][tok]
  bf16_t* Wb = (bf16_t*)p;  p += wB;
  bf16_t* bb = (bf16_t*)p;  p += 4 * H * 2;
  int* invp  = (int*)p;
  bf16_t* Att = Xp;

  const int nxc = (M * H) / 2048;             // 8192
  const int nw  = (H * H) / 2048 + 1;         // 129
  const int nprep = nxc + 4 * nw + (S + 255) / 256;
  prep_kernel<<<nprep, 256, 0, stream>>>(x, Xp, perm, invp,
                                         Wq, bq, Wk, bk, Wv, bv, Wo, bo,
                                         Wb, bb, S, H, M);

  dim3 g1(M / 256, H / 256, 3);
  gemm_qkv_kernel<<<g1, 512, 0, stream>>>(Xp, Wb, bb, Qp, Kp, Vt, S, H);

  dim3 g2(B * (S / 64));
  attn_kernel<<<g2, 256, 0, stream>>>(Qp, Kp, Vt, Att, S, H);

  dim3 g3(M / 256, H / 256, 1);
  gemm_o_kernel<<<g3, 512, 0, stream>>>(Att, Wb, bb, (float*)d_out, invp, S, H);
}

// Round 12
// 245.103 us; speedup vs baseline: 1.0074x; 1.0074x over previous
//
#include <hip/hip_runtime.h>
#include <hip/hip_bf16.h>

typedef __bf16 bf16_t;
typedef __attribute__((ext_vector_type(8))) __bf16 bf16x8;
typedef __attribute__((ext_vector_type(4))) __bf16 bf16x4;
typedef __attribute__((ext_vector_type(4))) float f32x4;

static __device__ __forceinline__ f32x4 mfma16(bf16x8 a, bf16x8 b, f32x4 c) {
  return __builtin_amdgcn_mfma_f32_16x16x32_bf16(a, b, c, 0, 0, 0);
}

// async global->LDS, 16 B per lane. LDS dest is wave-uniform base + lane*16.
static __device__ __forceinline__ void async16(const void* g, void* l) {
  __builtin_amdgcn_global_load_lds(
      (const __attribute__((address_space(1))) void*)g,
      (__attribute__((address_space(3))) void*)l, 16, 0, 0);
}

static __device__ __forceinline__ bf16x8 load8f(const float* __restrict__ fp) {
  float4 a = *(const float4*)fp;
  float4 b = *(const float4*)(fp + 4);
  bf16x8 r;
  r[0] = (bf16_t)a.x; r[1] = (bf16_t)a.y; r[2] = (bf16_t)a.z; r[3] = (bf16_t)a.w;
  r[4] = (bf16_t)b.x; r[5] = (bf16_t)b.y; r[6] = (bf16_t)b.z; r[7] = (bf16_t)b.w;
  return r;
}

// ---------------------------------------------------------------------------
// merged prep kernel (r10, kept). invperm + convert_x + convert_w.
// ---------------------------------------------------------------------------
__global__ __launch_bounds__(256) void prep_kernel(
    const float* __restrict__ x, bf16_t* __restrict__ Xp,
    const int* __restrict__ perm, int* __restrict__ invp,
    const float* Wq, const float* bq, const float* Wk, const float* bk,
    const float* Wv, const float* bv, const float* Wo, const float* bo,
    bf16_t* __restrict__ Wb, bf16_t* __restrict__ bb,
    int S, int H, int M)
{
  const int nxc = (M * H) / 2048;              // convert_x blocks (8192)
  const int nw  = (H * H) / 2048 + 1;          // per-matrix W blocks (129)
  const int bx = blockIdx.x;
  if (bx < nxc) {
    int m = bx * 4 + (threadIdx.x >> 6);
    int c = (threadIdx.x & 63) * 8;
    int b = m / S, i = m - b * S;
    long src = ((long)b * S + perm[i]) * H + c;
    *(bf16x8*)&Xp[(long)m * H + c] = load8f(x + src);
  } else if (bx < nxc + 4 * nw) {
    int t = bx - nxc;
    int z = t / nw, wx = t - z * nw;
    const float* W  = (z == 0) ? Wq : (z == 1) ? Wk : (z == 2) ? Wv : Wo;
    const float* bi = (z == 0) ? bq : (z == 1) ? bk : (z == 2) ? bv : bo;
    bf16_t* dst = Wb + (long)z * H * H;
    if (wx < nw - 1) {
      long e = (long)wx * 2048 + threadIdx.x * 8;
      *(bf16x8*)&dst[e] = load8f(W + e);
    } else {
      int e = threadIdx.x * 8;
      if (e < H) *(bf16x8*)&bb[z * H + e] = load8f(bi + e);
    }
  } else {
    int i = (bx - nxc - 4 * nw) * 256 + threadIdx.x;
    if (i < S) invp[perm[i]] = i;
  }
}

// ---------------------------------------------------------------------------
// GEMM core: r7 VERBATIM (4-phase counted-vmcnt pipeline, all 8 barriers/tile,
// coalesced LDS-transpose epilogues). The lockstep barriers are load-bearing
// for THROUGHPUT (r10 removal cost 17us on qkv under rocprof).
// ---------------------------------------------------------------------------
template<int MODE, bool GATHER>
__device__ __forceinline__ void gemm_core(
    unsigned char* __restrict__ smem,   // 128 KB
    const bf16_t* __restrict__ A, const bf16_t* __restrict__ W,
    const bf16_t* __restrict__ bias, void* __restrict__ C,
    const int* __restrict__ invp, int N, int K, int S)
{
  bf16_t (*At)[64] = (bf16_t(*)[64])smem;             // [512][64]
  bf16_t (*Bt)[64] = (bf16_t(*)[64])(smem + 65536);   // [512][64]

  const int bm = blockIdx.x * 256, bn = blockIdx.y * 256;
  const int tid = threadIdx.x, lane = tid & 63, w = tid >> 6;   // 8 waves
  const int qd = lane >> 4, ln = lane & 15, l7 = ln & 7;
  const int wm = w & 1, wn = w >> 1;            // 2M x 4N wave grid
  const int srow = lane >> 3;                   // 0..7 (row&7 of staged row)
  const int scol = ((lane & 7) ^ srow) * 8;     // swizzled global fetch chunk

  int ga[2][2], gb[2][2];
#pragma unroll
  for (int u = 0; u < 2; ++u) {
    int ix = w + 8 * u;                         // 0..15
    ga[0][u] = (ix & 7) + ((ix >> 3) << 4);
    ga[1][u] = ga[0][u] + 8;
    gb[0][u] = (ix & 3) + ((ix >> 2) << 3);
    gb[1][u] = gb[0][u] + 4;
  }
  long aoff[2][2], woff[2][2];
#pragma unroll
  for (int h = 0; h < 2; ++h)
#pragma unroll
    for (int u = 0; u < 2; ++u) {
      int mg = bm + ga[h][u] * 8 + srow;
      if (GATHER) { int b_ = mg / S; aoff[h][u] = ((long)b_ * S + invp[mg - b_ * S]) * K + scol; }
      else        { aoff[h][u] = (long)mg * K + scol; }
      woff[h][u] = (long)(bn + gb[h][u] * 8 + srow) * K + scol;
    }

  f32x4 acc[2][2][4][2];
#pragma unroll
  for (int a = 0; a < 2; ++a)
#pragma unroll
    for (int b = 0; b < 2; ++b)
#pragma unroll
      for (int i = 0; i < 4; ++i)
#pragma unroll
        for (int j = 0; j < 2; ++j)
          acc[a][b][i][j] = (f32x4){0.f, 0.f, 0.f, 0.f};

  bf16x8 af[4][2], bfr[2][2];
  const int NT = K >> 6;                         // 8 K-tiles for K=512

#define LOAD_A(RH)                                                            \
  _Pragma("unroll") for (int i = 0; i < 4; ++i)                               \
  _Pragma("unroll") for (int ks = 0; ks < 2; ++ks)                            \
    af[i][ks] = *(const bf16x8*)&At[sb + wm * 128 + (RH) * 64 + 16 * i + ln]  \
                                   [((ks * 4 + qd) ^ l7) * 8];
#define LOAD_B(CH)                                                            \
  _Pragma("unroll") for (int j = 0; j < 2; ++j)                               \
  _Pragma("unroll") for (int ks = 0; ks < 2; ++ks)                            \
    bfr[j][ks] = *(const bf16x8*)&Bt[sb + wn * 64 + (CH) * 32 + 16 * j + ln]  \
                                    [((ks * 4 + qd) ^ l7) * 8];
#define STAGE_A(HH)                                                           \
  if (st) {                                                                   \
    async16(&A[aoff[HH][0] + k2], &At[so + ga[HH][0] * 8][0]);                \
    async16(&A[aoff[HH][1] + k2], &At[so + ga[HH][1] * 8][0]);                \
  }
#define STAGE_B(CH)                                                           \
  if (st) {                                                                   \
    async16(&W[woff[CH][0] + k2], &Bt[so + gb[CH][0] * 8][0]);                \
    async16(&W[woff[CH][1] + k2], &Bt[so + gb[CH][1] * 8][0]);                \
  }
#define MFMA_Q(RH, CH)                                                        \
  __builtin_amdgcn_s_setprio(1);                                              \
  _Pragma("unroll") for (int i = 0; i < 4; ++i)                               \
  _Pragma("unroll") for (int j = 0; j < 2; ++j)                               \
  _Pragma("unroll") for (int ks = 0; ks < 2; ++ks) {                          \
    if (MODE == 2) acc[RH][CH][i][j] = mfma16(af[i][ks], bfr[j][ks], acc[RH][CH][i][j]); \
    else           acc[RH][CH][i][j] = mfma16(bfr[j][ks], af[i][ks], acc[RH][CH][i][j]); \
  }                                                                           \
  __builtin_amdgcn_s_setprio(0);
#define GATE2 asm volatile("s_waitcnt vmcnt(2)" ::: "memory")
#define GATE0 asm volatile("s_waitcnt vmcnt(0)" ::: "memory")
#define PH_MID                                                                \
  __builtin_amdgcn_s_barrier();                                               \
  asm volatile("s_waitcnt lgkmcnt(0)" ::: "memory");
#define PH_END __builtin_amdgcn_s_barrier();

  // prologue: stage tile 0 into slot 0 in deadline order A0,B0,B1,A1
  async16(&A[aoff[0][0]], &At[ga[0][0] * 8][0]);
  async16(&A[aoff[0][1]], &At[ga[0][1] * 8][0]);
  async16(&W[woff[0][0]], &Bt[gb[0][0] * 8][0]);
  async16(&W[woff[0][1]], &Bt[gb[0][1] * 8][0]);
  async16(&W[woff[1][0]], &Bt[gb[1][0] * 8][0]);
  async16(&W[woff[1][1]], &Bt[gb[1][1] * 8][0]);
  async16(&A[aoff[1][0]], &At[ga[1][0] * 8][0]);
  async16(&A[aoff[1][1]], &At[ga[1][1] * 8][0]);
  GATE2;
  __builtin_amdgcn_s_barrier();

  for (int kt = 0; kt < NT; ++kt) {
    const int sb = (kt & 1) << 8;          // compute-slot row base
    const int so = ((kt + 1) & 1) << 8;    // stage-slot row base
    const long k2 = (long)(kt + 1) << 6;
    const bool st = (kt + 1 < NT);

    // ---- phase 1: (rh=0, ch=0) ----
    GATE2;
    LOAD_A(0)
    LOAD_B(0)
    STAGE_A(0)
    PH_MID
    MFMA_Q(0, 0)
    PH_END
    // ---- phase 2: (rh=0, ch=1) ----
    if (st) { GATE2; } else { GATE0; }     // last tile: drain once here
    LOAD_B(1)
    STAGE_B(0)
    PH_MID
    MFMA_Q(0, 1)
    PH_END
    // ---- phase 3: (rh=1, ch=1) ----
    if (st) { GATE2; }
    LOAD_A(1)
    STAGE_B(1)
    PH_MID
    MFMA_Q(1, 1)
    PH_END
    // ---- phase 4: (rh=1, ch=0) ----
    if (st) { GATE2; }
    LOAD_B(0)
    STAGE_A(1)
    PH_MID
    MFMA_Q(1, 0)
    PH_END
  }

#undef LOAD_A
#undef LOAD_B
#undef STAGE_A
#undef STAGE_B
#undef MFMA_Q
#undef GATE2
#undef GATE0
#undef PH_MID
#undef PH_END

  // ---- coalesced epilogues via 16B-swizzled LDS transpose scratch ----
  if (MODE == 0) {
#pragma unroll
    for (int rh = 0; rh < 2; ++rh)
#pragma unroll
      for (int ch = 0; ch < 2; ++ch)
#pragma unroll
        for (int j = 0; j < 2; ++j) {
          bf16x4 b4 = *(const bf16x4*)&bias[bn + wn * 64 + ch * 32 + 16 * j + 4 * qd];
          int c16 = wn * 8 + ch * 4 + 2 * j + (qd >> 1);
#pragma unroll
          for (int i = 0; i < 4; ++i) {
            int m = wm * 128 + rh * 64 + 16 * i + ln;
            bf16x4 pk;
#pragma unroll
            for (int r = 0; r < 4; ++r) pk[r] = (bf16_t)(acc[rh][ch][i][j][r] + (float)b4[r]);
            *(bf16x4*)(smem + m * 512 + ((c16 ^ l7) * 16) + (qd & 1) * 8) = pk;
          }
        }
    __syncthreads();
#pragma unroll
    for (int k = 0; k < 16; ++k) {
      int row = w * 32 + 2 * k + (lane >> 5);
      int c = lane & 31;
      bf16x8 v = *(const bf16x8*)(smem + row * 512 + ((c ^ (row & 7)) * 16));
      *(bf16x8*)&((bf16_t*)C)[(long)(bm + row) * N + bn + c * 8] = v;
    }
  } else if (MODE == 1) {
#pragma unroll
    for (int rh = 0; rh < 2; ++rh) {
      if (rh) __syncthreads();
#pragma unroll
      for (int ch = 0; ch < 2; ++ch)
#pragma unroll
        for (int j = 0; j < 2; ++j) {
          bf16x4 b4 = *(const bf16x4*)&bias[bn + wn * 64 + ch * 32 + 16 * j + 4 * qd];
          int c16 = wn * 16 + ch * 8 + 4 * j + qd;
#pragma unroll
          for (int i = 0; i < 4; ++i) {
            int hrow = wm * 64 + 16 * i + ln;
            float4 pk = {acc[rh][ch][i][j][0] + (float)b4[0], acc[rh][ch][i][j][1] + (float)b4[1],
                         acc[rh][ch][i][j][2] + (float)b4[2], acc[rh][ch][i][j][3] + (float)b4[3]};
            *(float4*)(smem + hrow * 1024 + ((c16 ^ l7) * 16)) = pk;
          }
        }
      __syncthreads();
#pragma unroll
      for (int k = 0; k < 16; ++k) {
        int hrow = w + 8 * k;
        float4 v = *(const float4*)(smem + hrow * 1024 + (((lane) ^ (hrow & 7)) * 16));
        int gm = bm + (hrow >> 6) * 128 + rh * 64 + (hrow & 63);
        *(float4*)&((float*)C)[(long)gm * N + bn + lane * 4] = v;
      }
    }
  } else {
    const int heads = S >> 6;
    const int b_ = bm / S;
    const int h0 = (bm - b_ * S) >> 6;          // head base of this block
#pragma unroll
    for (int rh = 0; rh < 2; ++rh)
#pragma unroll
      for (int ch = 0; ch < 2; ++ch)
#pragma unroll
        for (int j = 0; j < 2; ++j) {
          int n = wn * 64 + ch * 32 + 16 * j + ln;
          float bv = (float)bias[bn + n];
#pragma unroll
          for (int i = 0; i < 4; ++i) {
            int c16 = wm * 16 + rh * 8 + 2 * i + (qd >> 1);
            bf16x4 pk;
#pragma unroll
            for (int r = 0; r < 4; ++r) pk[r] = (bf16_t)(acc[rh][ch][i][j][r] + bv);
            *(bf16x4*)(smem + n * 512 + ((c16 ^ l7) * 16) + (qd & 1) * 8) = pk;
          }
        }
    __syncthreads();
#pragma unroll
    for (int k = 0; k < 16; ++k) {
      int h4 = k >> 2;                            // local head (m block)
      int n = (w + 8 * (k & 3)) * 8 + (lane >> 3);
      int tc = lane & 7;                          // 16B tok-chunk
      bf16x8 v = *(const bf16x8*)(smem + n * 512 + (((h4 * 8 + tc) ^ (n & 7)) * 16));
      *(bf16x8*)&((bf16_t*)C)[(((long)(b_ * heads + h0 + h4) * N + bn + n) << 6) + tc * 8] = v;
    }
  }
}

__global__ __launch_bounds__(512, 2) void gemm_qkv_kernel(
    const bf16_t* __restrict__ Xp, const bf16_t* __restrict__ Wb,
    const bf16_t* __restrict__ bb,
    bf16_t* __restrict__ Qp, bf16_t* __restrict__ Kp, bf16_t* __restrict__ Vt,
    int S, int H)
{
  __shared__ __align__(16) unsigned char smem[131072];
  const int z = blockIdx.z;
  if (z < 2)
    gemm_core<0, false>(smem, Xp, Wb + (long)z * H * H, bb + z * H,
                        z ? (void*)Kp : (void*)Qp, nullptr, H, H, S);
  else
    gemm_core<2, false>(smem, Xp, Wb + 2L * H * H, bb + 2 * H, Vt, nullptr, H, H, S);
}

__global__ __launch_bounds__(512, 2) void gemm_o_kernel(
    const bf16_t* __restrict__ Att, const bf16_t* __restrict__ Wb,
    const bf16_t* __restrict__ bb, float* __restrict__ C,
    const int* __restrict__ invp, int S, int H)
{
  __shared__ __align__(16) unsigned char smem[131072];
  gemm_core<1, true>(smem, Att, Wb + 3L * H * H, bb + 3 * H, C, invp, H, H, S);
}

// ---------------------------------------------------------------------------
// attn v3 (r12): 3 blocks/CU. LDS 41 KB: Ks quarter [64][128] 16 KB (reused
// as out-scratch after QK), Vs quarter [128][64] 16 KB, P [64][72] 9 KB.
// Rationale: only attn changes ever moved the TIMED total (r6 v2: -7.5us);
// quarter-chunking extends the same occupancy lever 2->3 blocks/CU.
// K staged in 4 chan-quarters (QK accumulates same accs, same t order ->
// numerics identical); V^T in 4 row-quarters; output streamed per quarter
// through the scratch.
// Ledger (in-order vmcnt, per-thread): K(q+1) issued only after lgkm0+bar
// (all waves' K(q) reads retired). q<2 end: vmcnt(0)+bar -> K(q+1) landed.
// q==2 end: issue K3 then V0; vmcnt(4) forces K3 (V0 newest-4 flies under
// QK3+softmax); P4 end: vmcnt(0)+lgkm0+bar -> V0 + P visible, Ks dead.
// PV loop: PV(q)->scratch; lgkm0+bar (scratch visible, Vs reads done);
// issue V(q+1); store q (ds_read scratch -> global, ds_reads retire before
// each store issues); vmcnt(4) forces V(q+1) (this q's 4 stores newest);
// bar -> next PV safely reads Vs(q+1) and overwrites scratch.
// ---------------------------------------------------------------------------
__global__ __launch_bounds__(256) void attn_kernel(
    const bf16_t* __restrict__ Qp, const bf16_t* __restrict__ Kp,
    const bf16_t* __restrict__ Vt, bf16_t* __restrict__ Att,
    int S, int H)
{
  const int heads = S >> 6;
  const int b = blockIdx.x / heads;
  const int h = blockIdx.x % heads;
  const long qkbase = ((long)b * S + h * 64) * H;
  const long vbase  = (long)(b * heads + h) * H * 64;

  const int tid = threadIdx.x, lane = tid & 63, w = tid >> 6;
  const int qd = lane >> 4, ln = lane & 15;
  const int l7 = ln & 7;

  __shared__ bf16_t Ks[64 * 128];   // 16 KB K chan-quarter; later out-scratch
  __shared__ bf16_t Vs[128 * 64];   // 16 KB V^T row-quarter
  __shared__ bf16_t P[64][72];      // 9 KB softmax weights

#define STAGE_K(Q)                                                            \
  for (int u = 0; u < 4; ++u) {                                               \
    int row = 16 * w + 4 * u + (lane >> 4);                                   \
    int c = lane & 15;                                                        \
    async16(&Kp[qkbase + (long)row * H + (Q) * 128 + ((c ^ (row & 7)) * 8)],  \
            &Ks[(16 * w + 4 * u) * 128]);                                     \
  }
#define STAGE_V(Q)                                                            \
  for (int u = 0; u < 4; ++u) {                                               \
    int rowb = 32 * w + 8 * u;                                                \
    async16(&Vt[vbase + (long)((Q) * 128 + rowb + (lane >> 3)) * 64 +         \
                (((lane & 7) ^ ((lane >> 3) & 7)) * 8)],                      \
            &Vs[rowb * 64]);                                                  \
  }
#define QK_Q(Q)                                                               \
  for (int tl = 0; tl < 4; ++tl)                                              \
    for (int j = 0; j < 4; ++j) {                                             \
      bf16x8 kf = *(const bf16x8*)&Ks[(16 * j + ln) * 128 +                   \
                                      (((tl * 4 + qd) ^ l7) * 8)];            \
      accs[j] = mfma16(qf[(Q) * 4 + tl], kf, accs[j]);                        \
    }
#define LGKM0 asm volatile("s_waitcnt lgkmcnt(0)" ::: "memory")
#define BAR __builtin_amdgcn_s_barrier()

  // ---- P0: stage K0, load Q frags ----
  STAGE_K(0)
  asm volatile("" ::: "memory");     // pin K0 first in the vmcnt ledger
  bf16x8 qf[16];
  for (int t = 0; t < 16; ++t)
    qf[t] = *(const bf16x8*)&Qp[qkbase + (long)(16 * w + ln) * H + t * 32 + qd * 8];
  asm volatile("s_waitcnt vmcnt(16)" ::: "memory");   // K0 landed (Q flies)
  BAR;

  f32x4 accs[4];
  for (int j = 0; j < 4; ++j) accs[j] = (f32x4){0.f, 0.f, 0.f, 0.f};

  // ---- quarters 0..2 of QK ----
  QK_Q(0)
  LGKM0; BAR;                        // all waves' K0 reads retired
  STAGE_K(1)
  asm volatile("s_waitcnt vmcnt(0)" ::: "memory"); BAR;
  QK_Q(1)
  LGKM0; BAR;
  STAGE_K(2)
  asm volatile("s_waitcnt vmcnt(0)" ::: "memory"); BAR;
  QK_Q(2)
  LGKM0; BAR;
  STAGE_K(3)
  STAGE_V(0)                         // V0 flies under QK3 + softmax
  asm volatile("s_waitcnt vmcnt(4)" ::: "memory"); BAR;   // K3 landed

  // ---- quarter 3 + register softmax -> P ----
  QK_Q(3)
  const float rscale = rsqrtf((float)H);
  for (int r = 0; r < 4; ++r) {
    float s[4];
    for (int j = 0; j < 4; ++j) s[j] = accs[j][r] * rscale;
    float mx = fmaxf(fmaxf(s[0], s[1]), fmaxf(s[2], s[3]));
    mx = fmaxf(mx, __shfl_xor(mx, 1));
    mx = fmaxf(mx, __shfl_xor(mx, 2));
    mx = fmaxf(mx, __shfl_xor(mx, 4));
    mx = fmaxf(mx, __shfl_xor(mx, 8));
    float e[4], sum = 0.f;
    for (int j = 0; j < 4; ++j) {
      e[j] = (float)(bf16_t)__expf(s[j] - mx);
      sum += e[j];
    }
    sum += __shfl_xor(sum, 1);
    sum += __shfl_xor(sum, 2);
    sum += __shfl_xor(sum, 4);
    sum += __shfl_xor(sum, 8);
    float rs = 1.f / sum;
    for (int j = 0; j < 4; ++j)
      P[16 * w + qd * 4 + r][16 * j + ln] = (bf16_t)(e[j] * rs);
  }
  asm volatile("s_waitcnt vmcnt(0) lgkmcnt(0)" ::: "memory");
  BAR;   // V0 landed + P visible + Ks reads done -> Ks becomes scratch

  unsigned char* scratch = (unsigned char*)Ks;   // [64 rows][256 B]
  const int m = 16 * w + ln;
  const long orow = (long)b * S + h * 64;

#pragma unroll
  for (int q = 0; q < 4; ++q) {
    // PV quarter q: out chans q*128 + (16j + 4qd + r)
    f32x4 acco[8];
    for (int j = 0; j < 8; ++j) acco[j] = (f32x4){0.f, 0.f, 0.f, 0.f};
    for (int ks = 0; ks < 2; ++ks) {
      bf16x8 pf = *(const bf16x8*)&P[m][ks * 32 + qd * 8];
      for (int j = 0; j < 8; ++j) {
        int row = 16 * j + ln;
        bf16x8 vf = *(const bf16x8*)&Vs[row * 64 + (((ks * 4 + qd) ^ l7) * 8)];
        acco[j] = mfma16(vf, pf, acco[j]);
      }
    }
    for (int j = 0; j < 8; ++j) {
      int c16 = 2 * j + (qd >> 1);
      bf16x4 pk;
      for (int r = 0; r < 4; ++r) pk[r] = (bf16_t)acco[j][r];
      *(bf16x4*)(scratch + m * 256 + ((c16 ^ l7) * 16) + (qd & 1) * 8) = pk;
    }
    LGKM0; BAR;                      // scratch visible + Vs reads retired
    if (q < 3) STAGE_V(q + 1)        // overwrite Vs; lands under stores
    // store quarter q: 256 B contiguous runs
    for (int k = 0; k < 4; ++k) {
      int row = 16 * w + 4 * k + (lane >> 4);
      int c = lane & 15;
      bf16x8 v = *(const bf16x8*)(scratch + row * 256 + ((c ^ (row & 7)) * 16));
      *(bf16x8*)&Att[(orow + row) * H + q * 128 + c * 8] = v;
    }
    if (q < 3) {
      asm volatile("s_waitcnt vmcnt(4)" ::: "memory");  // V(q+1) landed
      BAR;
    }
  }

#undef STAGE_K
#undef STAGE_V
#undef QK_Q
#undef LGKM0
#undef BAR
}

extern "C" void kernel_launch(void* const* d_in, const int* in_sizes, int n_in,
                              void* d_out, int out_size, void* d_ws, size_t ws_size,
                              hipStream_t stream)
{
  const float* x  = (const float*)d_in[0];
  const float* Wq = (const float*)d_in[1]; const float* bq = (const float*)d_in[2];
  const float* Wk = (const float*)d_in[3]; const float* bk = (const float*)d_in[4];
  const float* Wv = (const float*)d_in[5]; const float* bv = (const float*)d_in[6];
  const float* Wo = (const float*)d_in[7]; const float* bo = (const float*)d_in[8];
  const int* perm = (const int*)d_in[9];

  const int S = in_sizes[9];                 // 4096
  const int H = in_sizes[2];                 // 512
  const int B = in_sizes[0] / (S * H);       // 8
  const int M = B * S;                       // 32768

  size_t bufB = (size_t)M * H * sizeof(bf16_t);          // 32 MB
  size_t wB   = 4 * (size_t)H * H * sizeof(bf16_t);
  size_t need = 256 + 4 * bufB + wB + 4 * H * 2 + (size_t)S * 4;
  if (ws_size < need) return;

  char* p = (char*)d_ws;  p += 256;
  bf16_t* Xp = (bf16_t*)p;  p += bufB;        // aliased as Att after QKV GEMM
  bf16_t* Qp = (bf16_t*)p;  p += bufB;
  bf16_t* Kp = (bf16_t*)p;  p += bufB;
  bf16_t* Vt = (bf16_t*)p;  p += bufB;        // V^T: [b][head][chan][tok]
  bf16_t* Wb = (bf16_t*)p;  p += wB;
  bf16_t* bb = (bf16_t*)p;  p += 4 * H * 2;
  int* invp  = (int*)p;
  bf16_t* Att = Xp;

  const int nxc = (M * H) / 2048;             // 8192
  const int nw  = (H * H) / 2048 + 1;         // 129
  const int nprep = nxc + 4 * nw + (S + 255) / 256;
  prep_kernel<<<nprep, 256, 0, stream>>>(x, Xp, perm, invp,
                                         Wq, bq, Wk, bk, Wv, bv, Wo, bo,
                                         Wb, bb, S, H, M);

  dim3 g1(M / 256, H / 256, 3);
  gemm_qkv_kernel<<<g1, 512, 0, stream>>>(Xp, Wb, bb, Qp, Kp, Vt, S, H);

  dim3 g2(B * (S / 64));
  attn_kernel<<<g2, 256, 0, stream>>>(Qp, Kp, Vt, Att, S, H);

  dim3 g3(M / 256, H / 256, 1);
  gemm_o_kernel<<<g3, 512, 0, stream>>>(Att, Wb, bb, (float*)d_out, invp, S, H);
}